// Round 14
// baseline (345.883 us; speedup 1.0000x reference)
//
#include <hip/hip_runtime.h>
#include <hip/hip_bf16.h>

#define BB 8
#define CC 16
#define EE 256
#define HH 256
#define WW 256
#define EMB_ROW (EE*9)

typedef __attribute__((ext_vector_type(8)))  __bf16 bf16x8;
typedef __attribute__((ext_vector_type(16))) float  f32x16;
typedef __attribute__((ext_vector_type(4)))  float  f32x4;

// ---- LDS layout (bytes) ----
// EPI : [16e][256w] f32 @ 0      (16384 B); first 9216 B overlaid by W
//       ([9][32e][16c] bf16) during init only (dead after afrag reads)
// XRING: 4 slots x [258wp][16c] bf16 @ 16384, slot stride 8256 B
#define LDS_EPI_OFF 0
#define LDS_X_OFF   16384
#define SLOT_BYTES  8256
#define LDS_TOTAL   (16384 + 4*8256)   // 49408 -> 3 blocks/CU

#define NTASK 2064   // 8 c-pairs * 258 wp per staged row

__device__ __forceinline__ unsigned pack_bf2(float a, float b) {
    union { __hip_bfloat162 h; unsigned u; } t;
    t.h.x = __float2bfloat16(a);
    t.h.y = __float2bfloat16(b);
    return t.u;
}

// X-ring address swizzle: 32B cell per wp; XOR byte bit4 with wp bit2 so
// consecutive-wp b128 reads cover all 8 LDS granules (write & read agree).
__device__ __forceinline__ int xswz(int wp, int inner) {
    return ((wp << 5) | inner) ^ ((wp & 4) << 2);
}

#define BARRIER() do { asm volatile("s_waitcnt lgkmcnt(0)" ::: "memory"); \
                       __builtin_amdgcn_s_barrier(); } while (0)

// grid: (BB, 16 hc, 8 ez)  block: 512 (8 waves). Block = 32e x 256w x 16h.
__global__ __launch_bounds__(512, 6) void conv_fused(
    const float* __restrict__ x,        // [B][C][H][W] f32
    const int*   __restrict__ indices,  // [B][C]
    const float* __restrict__ emb,      // [64][E*9] f32
    const float* __restrict__ bias,     // [E]
    float*       __restrict__ out)      // [B][E][H][W] f32
{
    __shared__ __align__(16) char smem[LDS_TOTAL];
    char*  WB  = smem;                       // overlay, init only
    float* EPI = (float*)(smem + LDS_EPI_OFF);
    char*  XB  = smem + LDS_X_OFF;

    const int b  = blockIdx.x;          // batch fastest -> XCD k handles batch k
    const int hc = blockIdx.y;          // 16 h-chunks of 16
    const int ez = blockIdx.z;          // 8 e-tiles of 32
    const int tid   = threadIdx.x;
    const int lane  = tid & 63;
    const int wid   = tid >> 6;         // 0..7
    const int l31   = lane & 31;
    const int lhalf = lane >> 5;
    const int e0 = ez * 32;
    const int w0 = wid * 32;
    const int h0 = hc * 16;

    // ---- W gather into overlay: thread (e = tid>>4, c = tid&15), 9 taps
    {
        const int e = tid >> 4, c = tid & 15;
        const int idx = indices[b * CC + c];
        const float* wrow = emb + (size_t)idx * EMB_ROW + (size_t)(e0 + e) * 9;
        #pragma unroll
        for (int tap = 0; tap < 9; ++tap) {
            *reinterpret_cast<__hip_bfloat16*>(WB + tap * 1024 + e * 32 + c * 2) =
                __float2bfloat16(wrow[tap]);
        }
    }

    // ---- x staging: T14 split (issue loads early, ds_write late) ----
    float r0[5], r1[5];
    auto issue_loads = [&](int ir) {
        #pragma unroll
        for (int k = 0; k < 5; ++k) {
            const int u = tid + 512 * k;
            if (u < NTASK) {
                const int cp = u / 258;
                const int wp = u - cp * 258;
                const int iw = wp - 1;
                const bool v = ((unsigned)iw < 256u) && ((unsigned)ir < 256u);
                const float* p = x + (((size_t)(b * CC + 2 * cp) * HH + (ir & 255)) * WW + (iw & 255));
                r0[k] = v ? p[0] : 0.f;
                r1[k] = v ? p[HH * WW] : 0.f;
            }
        }
    };
    auto write_stage = [&](int ir) {
        const int slot = (ir + 1) & 3;
        #pragma unroll
        for (int k = 0; k < 5; ++k) {
            const int u = tid + 512 * k;
            if (u < NTASK) {
                const int cp = u / 258;
                const int wp = u - cp * 258;
                *reinterpret_cast<unsigned*>(XB + slot * SLOT_BYTES + xswz(wp, cp << 2)) =
                    pack_bf2(r0[k], r1[k]);
            }
        }
    };

    // prologue: rows h0-1, h0, h0+1 staged; loads for h0+2 left in flight
    issue_loads(h0 - 1); write_stage(h0 - 1);
    issue_loads(h0);     write_stage(h0);
    issue_loads(h0 + 1); write_stage(h0 + 1);
    issue_loads(h0 + 2);
    BARRIER();

    // A-frags from W overlay (all waves read BEFORE the loop's first barrier;
    // EPI scatter only happens after that barrier -> overlay reuse is safe)
    bf16x8 afrag[9];
    #pragma unroll
    for (int tap = 0; tap < 9; ++tap)
        afrag[tap] = *reinterpret_cast<const bf16x8*>(WB + tap * 1024 + l31 * 32 + lhalf * 16);

    // bias for the 4 e-rows this wave stores: pass0 rows 2wid,2wid+1; pass1 +16
    float bb0[2], bb1[2];
    #pragma unroll
    for (int i = 0; i < 2; ++i) {
        bb0[i] = bias[e0 + 2 * wid + i];
        bb1[i] = bias[e0 + 16 + 2 * wid + i];
    }

    for (int h = h0; h < h0 + 16; ++h) {
        if (h + 2 <= h0 + 16) write_stage(h + 2);
        if (h + 3 <= h0 + 16) issue_loads(h + 3);
        BARRIER();                                   // b1: ring slot ready

        f32x16 acc;
        #pragma unroll
        for (int r = 0; r < 16; ++r) acc[r] = 0.f;

        #pragma unroll
        for (int kh = 0; kh < 3; ++kh) {
            const char* base = XB + ((h + kh) & 3) * SLOT_BYTES;  // slot(ir=h-1+kh)
            #pragma unroll
            for (int kw = 0; kw < 3; ++kw) {
                const int wp = w0 + l31 + kw;
                bf16x8 bfrag = *reinterpret_cast<const bf16x8*>(base + xswz(wp, lhalf << 4));
                acc = __builtin_amdgcn_mfma_f32_32x32x16_bf16(afrag[kh * 3 + kw], bfrag, acc, 0, 0, 0);
            }
        }

        // ---- epilogue pass 0: e-rows 0..15 (regs r<8) ----
        #pragma unroll
        for (int r = 0; r < 8; ++r) {
            const int erow = (r & 3) + 8 * (r >> 2) + 4 * lhalf;   // 0..15
            EPI[erow * 256 + w0 + l31] = acc[r];
        }
        BARRIER();                                   // b2: pass0 tile complete
        #pragma unroll
        for (int i = 0; i < 2; ++i) {
            const int row = 2 * wid + i;
            f32x4 v = *reinterpret_cast<const f32x4*>(&EPI[row * 256 + lane * 4]);
            v += bb0[i];
            __builtin_nontemporal_store(v,
                reinterpret_cast<f32x4*>(&out[((size_t)(b * EE + e0 + row) * HH + h) * WW + lane * 4]));
        }
        BARRIER();                                   // b3: pass0 reads drained

        // ---- epilogue pass 1: e-rows 16..31 (regs r>=8) ----
        #pragma unroll
        for (int r = 8; r < 16; ++r) {
            const int erow = (r & 3) + 8 * (r >> 2) + 4 * lhalf - 16;  // 0..15
            EPI[erow * 256 + w0 + l31] = acc[r];
        }
        BARRIER();                                   // b4: pass1 tile complete
        #pragma unroll
        for (int i = 0; i < 2; ++i) {
            const int row = 2 * wid + i;
            f32x4 v = *reinterpret_cast<const f32x4*>(&EPI[row * 256 + lane * 4]);
            v += bb1[i];
            __builtin_nontemporal_store(v,
                reinterpret_cast<f32x4*>(&out[((size_t)(b * EE + e0 + 16 + row) * HH + h) * WW + lane * 4]));
        }
        // pass1 EPI reads are drained by each wave's own lgkmcnt(0) at next b1
    }
}

extern "C" void kernel_launch(void* const* d_in, const int* in_sizes, int n_in,
                              void* d_out, int out_size, void* d_ws, size_t ws_size,
                              hipStream_t stream) {
    const float* x       = (const float*)d_in[0];
    const int*   indices = (const int*)  d_in[1];
    const float* emb     = (const float*)d_in[2];
    const float* bias    = (const float*)d_in[3];
    float*       out     = (float*)d_out;

    conv_fused<<<dim3(BB, 16, 8), dim3(512), 0, stream>>>(x, indices, emb, bias, out);
}

// Round 15
// 111.960 us; speedup vs baseline: 3.0893x; 3.0893x over previous
//
#include <hip/hip_runtime.h>
#include <hip/hip_bf16.h>

#define BB 8
#define CC 16
#define EE 256
#define HH 256
#define WW 256
#define EMB_ROW (EE*9)

typedef __attribute__((ext_vector_type(8)))  __bf16 bf16x8;
typedef __attribute__((ext_vector_type(16))) float  f32x16;
typedef __attribute__((ext_vector_type(4)))  float  f32x4;

// ---- LDS layout (bytes) ----
// W    : [9][32e][16c] bf16   @ 0       (9216 B)
// XRING: 4 slots x [258wp][16c] bf16 @ 9216, slot stride 8256 B
// EPI  : [32e][256w] f32      @ 42240   (32768 B)
#define LDS_X_OFF   9216
#define SLOT_BYTES  8256
#define LDS_EPI_OFF 42240
#define LDS_TOTAL   75008

#define NTASK 2064   // 8 c-pairs * 258 wp per staged row

__device__ __forceinline__ unsigned pack_bf2(float a, float b) {
    union { __hip_bfloat162 h; unsigned u; } t;
    t.h.x = __float2bfloat16(a);
    t.h.y = __float2bfloat16(b);
    return t.u;
}

// X-ring address swizzle: 32B cell per wp; XOR byte bit4 with wp bit2 so
// consecutive-wp b128 reads cover all 8 LDS granules (write & read agree).
__device__ __forceinline__ int xswz(int wp, int inner) {
    return ((wp << 5) | inner) ^ ((wp & 4) << 2);
}

// grid: (BB, 16 hc, 8 ez)  block: 512 (8 waves). Block = 32e x 256w x 16h.
// 2 blocks/CU (75KB LDS), ~100 VGPR: the feasible operating point (R14
// showed 3 blocks/CU forces a 40-VGPR cap -> catastrophic spills).
__global__ __launch_bounds__(512, 4) void conv_fused(
    const float* __restrict__ x,        // [B][C][H][W] f32
    const int*   __restrict__ indices,  // [B][C]
    const float* __restrict__ emb,      // [64][E*9] f32
    const float* __restrict__ bias,     // [E]
    float*       __restrict__ out)      // [B][E][H][W] f32
{
    __shared__ __align__(16) char smem[LDS_TOTAL];
    char*  WB  = smem;
    char*  XB  = smem + LDS_X_OFF;
    float* EPI = (float*)(smem + LDS_EPI_OFF);

    const int b  = blockIdx.x;          // batch fastest -> XCD k handles batch k
    const int hc = blockIdx.y;          // 16 h-chunks of 16
    const int ez = blockIdx.z;          // 8 e-tiles of 32
    const int tid   = threadIdx.x;
    const int lane  = tid & 63;
    const int wid   = tid >> 6;         // 0..7
    const int l31   = lane & 31;
    const int lhalf = lane >> 5;
    const int e0 = ez * 32;
    const int w0 = wid * 32;
    const int h0 = hc * 16;

    // ---- W gather: thread (e = tid>>4, c = tid&15) pulls 9 contiguous taps
    {
        const int e = tid >> 4, c = tid & 15;
        const int idx = indices[b * CC + c];
        const float* wrow = emb + (size_t)idx * EMB_ROW + (size_t)(e0 + e) * 9;
        #pragma unroll
        for (int tap = 0; tap < 9; ++tap) {
            *reinterpret_cast<__hip_bfloat16*>(WB + tap * 1024 + e * 32 + c * 2) =
                __float2bfloat16(wrow[tap]);
        }
    }

    // ---- x staging: T14 split (issue loads early, ds_write late) ----
    float r0[5], r1[5];
    auto issue_loads = [&](int ir) {
        #pragma unroll
        for (int k = 0; k < 5; ++k) {
            const int u = tid + 512 * k;
            if (u < NTASK) {
                const int cp = u / 258;
                const int wp = u - cp * 258;
                const int iw = wp - 1;
                const bool v = ((unsigned)iw < 256u) && ((unsigned)ir < 256u);
                const float* p = x + (((size_t)(b * CC + 2 * cp) * HH + (ir & 255)) * WW + (iw & 255));
                r0[k] = v ? p[0] : 0.f;
                r1[k] = v ? p[HH * WW] : 0.f;
            }
        }
    };
    auto write_stage = [&](int ir) {
        const int slot = (ir + 1) & 3;
        #pragma unroll
        for (int k = 0; k < 5; ++k) {
            const int u = tid + 512 * k;
            if (u < NTASK) {
                const int cp = u / 258;
                const int wp = u - cp * 258;
                *reinterpret_cast<unsigned*>(XB + slot * SLOT_BYTES + xswz(wp, cp << 2)) =
                    pack_bf2(r0[k], r1[k]);
            }
        }
    };

    // prologue: rows h0-1, h0, h0+1 staged; loads for h0+2 left in flight
    issue_loads(h0 - 1); write_stage(h0 - 1);
    issue_loads(h0);     write_stage(h0);
    issue_loads(h0 + 1); write_stage(h0 + 1);
    issue_loads(h0 + 2);
    asm volatile("s_waitcnt lgkmcnt(0)" ::: "memory");
    __builtin_amdgcn_s_barrier();

    // A-frags from LDS W (once): lane l -> e = e0+l31, c = lhalf*8..+8
    bf16x8 afrag[9];
    #pragma unroll
    for (int tap = 0; tap < 9; ++tap)
        afrag[tap] = *reinterpret_cast<const bf16x8*>(WB + tap * 1024 + l31 * 32 + lhalf * 16);

    float bb[4];
    #pragma unroll
    for (int i = 0; i < 4; ++i) bb[i] = bias[e0 + wid * 4 + i];

    for (int h = h0; h < h0 + 16; ++h) {
        // write row h+2 (loads issued last iter), then issue loads for h+3
        if (h + 2 <= h0 + 16) write_stage(h + 2);
        if (h + 3 <= h0 + 16) issue_loads(h + 3);
        asm volatile("s_waitcnt lgkmcnt(0)" ::: "memory");
        __builtin_amdgcn_s_barrier();

        f32x16 acc;
        #pragma unroll
        for (int r = 0; r < 16; ++r) acc[r] = 0.f;

        #pragma unroll
        for (int kh = 0; kh < 3; ++kh) {
            const char* base = XB + ((h + kh) & 3) * SLOT_BYTES;  // slot(ir=h-1+kh)
            #pragma unroll
            for (int kw = 0; kw < 3; ++kw) {
                const int wp = w0 + l31 + kw;
                bf16x8 bfrag = *reinterpret_cast<const bf16x8*>(base + xswz(wp, lhalf << 4));
                acc = __builtin_amdgcn_mfma_f32_32x32x16_bf16(afrag[kh * 3 + kw], bfrag, acc, 0, 0, 0);
            }
        }

        // epilogue scatter (LDS), then coalesced 1KB-row nt stores
        #pragma unroll
        for (int r = 0; r < 16; ++r) {
            const int erow = (r & 3) + 8 * (r >> 2) + 4 * lhalf;
            EPI[erow * 256 + w0 + l31] = acc[r];
        }
        asm volatile("s_waitcnt lgkmcnt(0)" ::: "memory");
        __builtin_amdgcn_s_barrier();

        #pragma unroll
        for (int i = 0; i < 4; ++i) {
            const int e = wid * 4 + i;
            f32x4 v = *reinterpret_cast<const f32x4*>(&EPI[e * 256 + lane * 4]);
            v += bb[i];
            __builtin_nontemporal_store(v,
                reinterpret_cast<f32x4*>(&out[((size_t)(b * EE + e0 + e) * HH + h) * WW + lane * 4]));
        }
    }
}

extern "C" void kernel_launch(void* const* d_in, const int* in_sizes, int n_in,
                              void* d_out, int out_size, void* d_ws, size_t ws_size,
                              hipStream_t stream) {
    const float* x       = (const float*)d_in[0];
    const int*   indices = (const int*)  d_in[1];
    const float* emb     = (const float*)d_in[2];
    const float* bias    = (const float*)d_in[3];
    float*       out     = (float*)d_out;

    conv_fused<<<dim3(BB, 16, 8), dim3(512), 0, stream>>>(x, indices, emb, bias, out);
}